// Round 12
// baseline (408.144 us; speedup 1.0000x reference)
//
#include <hip/hip_runtime.h>

#define M_TOTAL 12544
#define IN_D 768
#define OUT_D 768
#define NUM_F 8
#define NP 9
#define KTOT (IN_D * NP)            // 6912

#define BM 128
#define BN 128
#define BK 32
#define MT_TILES (M_TOTAL / BM)     // 98
#define NT_TILES (OUT_D / BN)       // 6
#define PJ (IN_D / BK)              // 24 jj slices
#define KT_TILES (KTOT / BK)        // 216, k-order kt' = jj*9 + p
#define GRANA 512                   // 16B granules per 128x32 bf16 tile

typedef __attribute__((ext_vector_type(8))) short short8;
typedef __attribute__((ext_vector_type(4))) float f32x4;

__device__ __forceinline__ unsigned short f2bf(float f) {
  unsigned u = __float_as_uint(f);
  u += 0x7fff + ((u >> 16) & 1);   // RNE
  return (unsigned short)(u >> 16);
}

// ---------------------------------------------------------------------------
// pack_b_t: Bt[(nt*216 + jj*9 + p)*512 + g], g = kc*128+row.
// val = p==0 ? bw[o][i] : cw[p-1][o][i] * ssp[o] * coef[i][p-1]
// (coef folded into B so the fused GEMM's A-activation is coef-free)
// o = nt*128+row, i = jj*32 + kc*8 + e.
// ---------------------------------------------------------------------------
__global__ __launch_bounds__(256) void pack_b_t(
    const float* __restrict__ bw, const float* __restrict__ ssp,
    const float* __restrict__ cw, const float* __restrict__ coef,
    short8* __restrict__ Bt)
{
  int gg = blockIdx.x * 256 + threadIdx.x;   // [0, 6*216*512)
  int nt = gg / (KT_TILES * GRANA);
  int rem = gg % (KT_TILES * GRANA);
  int kt = rem >> 9;
  int g = rem & 511;
  int row = g & 127, kc = g >> 7;
  int o = nt * 128 + row;
  int jj = kt / NP, p = kt % NP;
  int i0 = jj * 32 + kc * 8;
  short8 s;
  if (p == 0) {
    const float* src = bw + (size_t)o * IN_D + i0;
    f32x4 v0 = ((const f32x4*)src)[0], v1 = ((const f32x4*)src)[1];
    #pragma unroll
    for (int e = 0; e < 4; ++e) {
      s[e]     = (short)f2bf(v0[e]);
      s[e + 4] = (short)f2bf(v1[e]);
    }
  } else {
    const float* src = cw + ((size_t)(p - 1) * OUT_D + o) * IN_D + i0;
    float fac = ssp[o];
    f32x4 v0 = ((const f32x4*)src)[0], v1 = ((const f32x4*)src)[1];
    #pragma unroll
    for (int e = 0; e < 4; ++e) {
      s[e]     = (short)f2bf(v0[e] * fac * coef[(size_t)(i0 + e) * NUM_F + (p - 1)]);
      s[e + 4] = (short)f2bf(v1[e] * fac * coef[(size_t)(i0 + 4 + e) * NUM_F + (p - 1)]);
    }
  }
  Bt[gg] = s;
}

// ---------------------------------------------------------------------------
// skan_fused_gemm: A-activation fused into the GEMM.
// 128x128 tile, BK=32, 4 waves (2x2 of 64x64), dbuf A/B LDS.
// x slab (128 rows x 32 cols f32, 16 KB) staged via global_load_lds with
// chunk swizzle (phys_chunk = (log_chunk + row) & 7): linear LDS dest +
// pre-swizzled global source + swizzled read (rule-21 both-sides).
// Each thread caches its 16 x-floats in VGPR for the 9 plane-steps of a jj.
// Per k-step: compute 16 activations -> ds_write 2 granules (next buf),
// B via sequential global_load_lds, then frag reads + 16 MFMA (cur buf).
// ---------------------------------------------------------------------------
__global__ __launch_bounds__(256, 2) void skan_fused_gemm(
    const float* __restrict__ x, const float* __restrict__ grid,
    const short8* __restrict__ Bt, const float* __restrict__ ssp,
    const float* __restrict__ cb, float* __restrict__ out)
{
  __shared__ __align__(16) float xs[128 * 32];   // 16 KB, chunk-swizzled
  __shared__ short8 Asm[2][GRANA];               // 16 KB
  __shared__ short8 Bsm[2][GRANA];               // 16 KB
  __shared__ float bias_sm[BN];

  // bijective XCD swizzle (nwg=588 = 8*73+4)
  const int bid0 = blockIdx.x;
  const int xcd = bid0 & 7;
  const int idx = bid0 >> 3;
  const int wgid = (xcd < 4 ? xcd * 74 : 4 * 74 + (xcd - 4) * 73) + idx;
  const int tm = wgid / NT_TILES, tn = wgid % NT_TILES;
  const int m0 = tm * BM, n0 = tn * BN;

  const int tid = threadIdx.x;
  const int lane = tid & 63, wid = tid >> 6;
  const int wm = wid >> 1, wn = wid & 1;
  const int lrow = lane & 15, lkb = lane >> 4;
  const int row_t = tid & 127;        // thread's granule row
  const int kc0 = (tid >> 7) * 2;     // thread's granule k-chunk pair

  if (tid < BN) {
    int o = n0 + tid;
    float s = 0.f;
    #pragma unroll
    for (int f = 0; f < NUM_F; ++f) s += cb[f * OUT_D + o];
    bias_sm[tid] = s * ssp[o];
  }

  float gv[8];
  #pragma unroll
  for (int p = 0; p < 8; ++p) gv[p] = grid[p];

  // ---- staging helpers (macros keep all indices compile-time static) ----
  // x slab: instr k, thread t fills phys float [k*1024 + t*4 .. +3]
  // = row k*32+(t>>3), phys chunk t&7; global source chunk (cphys - row)&7.
#define STAGE_X(jjn)                                                          \
  { _Pragma("unroll") for (int k = 0; k < 4; ++k) {                           \
      int rrow = k * 32 + (tid >> 3);                                         \
      int cphys = tid & 7;                                                    \
      int clog = (cphys - rrow) & 7;                                          \
      const float* sxp = x + (size_t)(m0 + rrow) * IN_D + (jjn) * 32 + clog * 4; \
      __builtin_amdgcn_global_load_lds(                                       \
          (const __attribute__((address_space(1))) void*)sxp,                 \
          (__attribute__((address_space(3))) void*)&xs[k * 1024 + tid * 4],   \
          16, 0, 0);                                                          \
    } }

  // read thread's 16 x-floats (logical chunks kc0*2..+3) with read-side swizzle
#define READ_XR(arr)                                                          \
  { _Pragma("unroll") for (int q = 0; q < 4; ++q) {                           \
      int cphys = ((kc0 * 2 + q) + row_t) & 7;                                \
      arr[q] = *(const f32x4*)&xs[row_t * 32 + cphys * 4];                    \
    } }

  // activation: plane pn (literal after unroll) from 16 f32 -> 2 bf16 granules
#define ACT(pn, arr, d0, d1)                                                  \
  {                                                                           \
    if ((pn) == 0) {                                                          \
      _Pragma("unroll") for (int e = 0; e < 4; ++e) {                         \
        float t0 = arr[0][e], t1 = arr[1][e], t2 = arr[2][e], t3 = arr[3][e]; \
        d0[e]     = (short)f2bf(t0 / (1.f + __expf(-t0)));                    \
        d0[e + 4] = (short)f2bf(t1 / (1.f + __expf(-t1)));                    \
        d1[e]     = (short)f2bf(t2 / (1.f + __expf(-t2)));                    \
        d1[e + 4] = (short)f2bf(t3 / (1.f + __expf(-t3)));                    \
      }                                                                       \
    } else {                                                                  \
      float gg = gv[(pn) - 1];                                                \
      _Pragma("unroll") for (int e = 0; e < 4; ++e) {                         \
        d0[e]     = (short)f2bf(__sinf(arr[0][e] * gg));                      \
        d0[e + 4] = (short)f2bf(__sinf(arr[1][e] * gg));                      \
        d1[e]     = (short)f2bf(__sinf(arr[2][e] * gg));                      \
        d1[e + 4] = (short)f2bf(__sinf(arr[3][e] * gg));                      \
      }                                                                       \
    }                                                                         \
  }

#define STAGE_B(buf, bsrc)                                                    \
  { _Pragma("unroll") for (int c = 0; c < 2; ++c) {                           \
      __builtin_amdgcn_global_load_lds(                                       \
          (const __attribute__((address_space(1))) void*)((bsrc) + c * 256 + tid), \
          (__attribute__((address_space(3))) void*)&Bsm[buf][c * 256 + tid],  \
          16, 0, 0);                                                          \
    } }

  const short8* bptr = Bt + (size_t)tn * KT_TILES * GRANA;

  f32x4 xr[4], yr[4];
  f32x4 acc[4][4];
  #pragma unroll
  for (int i = 0; i < 4; ++i)
    #pragma unroll
    for (int j = 0; j < 4; ++j)
      acc[i][j] = (f32x4){0.f, 0.f, 0.f, 0.f};

  // ---- prologue: x[0] + B[0] staged; act plane 0 into Asm[0] ----
  STAGE_X(0);
  STAGE_B(0, bptr);
  __syncthreads();                 // x slab + B tile 0 landed
  READ_XR(xr);
  {
    short8 a0, a1;
    ACT(0, xr, a0, a1);
    Asm[0][kc0 * 128 + row_t] = a0;
    Asm[0][(kc0 + 1) * 128 + row_t] = a1;
  }

  // ---- main loop: t = jj*9 + p ----
  int t = 0;
  for (int jj = 0; jj < PJ; ++jj) {
    #pragma unroll
    for (int p = 0; p < 9; ++p, ++t) {
      const int cur = t & 1;
      const int nxt = cur ^ 1;
      __syncthreads();             // [cur] fully staged; [nxt] reads drained
      if (t + 1 < KT_TILES) {
        if (p == 2 && jj < PJ - 1) STAGE_X(jj + 1);
        STAGE_B(nxt, bptr + (size_t)(t + 1) * GRANA);
        if (p == 7 && jj < PJ - 1) READ_XR(yr);
        short8 a0, a1;
        if (p < 8) { ACT(p + 1, xr, a0, a1); }
        else       { ACT(0, yr, a0, a1); }
        Asm[nxt][kc0 * 128 + row_t] = a0;
        Asm[nxt][(kc0 + 1) * 128 + row_t] = a1;
      }
      // consume [cur]
      short8 af[4], bfr[4];
      #pragma unroll
      for (int q = 0; q < 4; ++q) {
        int base = lkb * 128 + q * 16 + lrow;
        af[q]  = Asm[cur][base + wm * 64];
        bfr[q] = Bsm[cur][base + wn * 64];
      }
      #pragma unroll
      for (int i = 0; i < 4; ++i)
        #pragma unroll
        for (int j = 0; j < 4; ++j)
          acc[i][j] = __builtin_amdgcn_mfma_f32_16x16x32_bf16(af[i], bfr[j], acc[i][j], 0, 0, 0);
    }
    if (jj < PJ - 1) {
      #pragma unroll
      for (int q = 0; q < 4; ++q) xr[q] = yr[q];
    }
  }

  // epilogue: C/D layout col=lane&15, row=(lane>>4)*4+reg (verified round 1)
  #pragma unroll
  for (int i = 0; i < 4; ++i) {
    int row = m0 + wm * 64 + i * 16 + lkb * 4;
    #pragma unroll
    for (int j = 0; j < 4; ++j) {
      int col = n0 + wn * 64 + j * 16 + lrow;
      float bia = bias_sm[wn * 64 + j * 16 + lrow];
      float* op = out + (size_t)row * OUT_D + col;
      op[0 * OUT_D] = acc[i][j][0] + bia;
      op[1 * OUT_D] = acc[i][j][1] + bia;
      op[2 * OUT_D] = acc[i][j][2] + bia;
      op[3 * OUT_D] = acc[i][j][3] + bia;
    }
  }
#undef STAGE_X
#undef READ_XR
#undef ACT
#undef STAGE_B
}

extern "C" void kernel_launch(void* const* d_in, const int* in_sizes, int n_in,
                              void* d_out, int out_size, void* d_ws, size_t ws_size,
                              hipStream_t stream) {
  (void)in_sizes; (void)n_in; (void)out_size; (void)ws_size;
  const float* x    = (const float*)d_in[0];
  const float* bw   = (const float*)d_in[1];
  const float* grid = (const float*)d_in[2];
  const float* ssp  = (const float*)d_in[3];
  const float* coef = (const float*)d_in[4];
  const float* cw   = (const float*)d_in[5];
  const float* cb   = (const float*)d_in[6];
  float* out = (float*)d_out;

  short8* Bw = (short8*)d_ws;   // 6*216*512*16 = 10.6 MB

  pack_b_t<<<(NT_TILES * KT_TILES * GRANA) / 256, 256, 0, stream>>>(
      bw, ssp, cw, coef, Bw);
  skan_fused_gemm<<<MT_TILES * NT_TILES, 256, 0, stream>>>(
      x, grid, Bw, ssp, cb, out);
}

// Round 13
// 292.786 us; speedup vs baseline: 1.3940x; 1.3940x over previous
//
#include <hip/hip_runtime.h>

#define M_TOTAL 12544
#define IN_D 768
#define OUT_D 768
#define NUM_F 8
#define NP 9
#define KTOT (IN_D * NP)            // 6912

#define BM 128
#define BN 128
#define BK 32
#define MT_TILES (M_TOTAL / BM)     // 98
#define NT_TILES (OUT_D / BN)       // 6
#define PJ (IN_D / BK)              // 24 k-chunks per plane
#define KT_TILES (KTOT / BK)        // 216
#define GRANA 512                   // 16B granules per 128x32 bf16 tile

typedef __attribute__((ext_vector_type(8))) short short8;
typedef __attribute__((ext_vector_type(4))) float f32x4;

__device__ __forceinline__ unsigned short f2bf(float f) {
  unsigned u = __float_as_uint(f);
  u += 0x7fff + ((u >> 16) & 1);   // RNE
  return (unsigned short)(u >> 16);
}

// ---------------------------------------------------------------------------
// pack_a_t: one block per (mt, jj) = (m-tile, 32-col slice). Computes all 9
// planes from one x staging: x read from HBM exactly once.
// At[(mt*216 + p*24 + jj)*512 + kc*128 + row] = bf16 A[row][jj*32+kc*8 .. +7]
// LDS transposed (xs[col][row], 129 pitch): stage writes and granule reads
// both conflict-free. (Measured round 7: part of 119us non-GEMM blob, OK.)
// ---------------------------------------------------------------------------
__global__ __launch_bounds__(256) void pack_a_t(
    const float* __restrict__ x, const float* __restrict__ grid,
    const float* __restrict__ coef, short8* __restrict__ At)
{
  __shared__ float xs[32][129];
  __shared__ float cs[32][8];

  const int bid = blockIdx.x;
  const int mt = bid / PJ, jj = bid % PJ;
  const int tid = threadIdx.x;

  // stage x rows 0..127, cols jj*32..+31 (8 lanes x 16B cover one row's 128B)
  {
    const int c = tid & 7;          // 16B chunk in row
    const int r0 = tid >> 3;        // row within 32-row group
    #pragma unroll
    for (int q = 0; q < 4; ++q) {
      int r = q * 32 + r0;
      f32x4 v = *(const f32x4*)(x + (size_t)(mt * 128 + r) * IN_D + jj * 32 + c * 4);
      #pragma unroll
      for (int e = 0; e < 4; ++e) xs[c * 4 + e][r] = v[e];
    }
  }
  cs[tid >> 3][tid & 7] = coef[(size_t)(jj * 32 + (tid >> 3)) * NUM_F + (tid & 7)];
  __syncthreads();

  for (int p = 0; p < NP; ++p) {
    short8* dst = At + ((size_t)mt * KT_TILES + p * PJ + jj) * GRANA;
    float gf = (p > 0) ? grid[p - 1] : 0.f;
    #pragma unroll
    for (int c2 = 0; c2 < 2; ++c2) {
      int g = c2 * 256 + tid, row = g & 127, kc = g >> 7;
      short8 s;
      if (p == 0) {
        #pragma unroll
        for (int e = 0; e < 8; ++e) {
          float t = xs[kc * 8 + e][row];
          s[e] = (short)f2bf(t / (1.f + __expf(-t)));
        }
      } else {
        #pragma unroll
        for (int e = 0; e < 8; ++e)
          s[e] = (short)f2bf(__sinf(xs[kc * 8 + e][row] * gf) * cs[kc * 8 + e][p - 1]);
      }
      dst[g] = s;   // consecutive lanes -> consecutive 16B: coalesced
    }
  }
}

// ---------------------------------------------------------------------------
// pack_b_t (REWRITTEN): one block per (nt, kt). Round-7 version issued 64
// independent 32B gathers/wave at 3072B stride (request-rate bound, est.
// ~50us). Now: stage the 128x32 f32 slice via 8-lanes-per-row 128B-segment
// reads (8 transactions/instr), transpose in LDS (conflict-free, same as
// pack_a), write granules coalesced.
// Bt[(nt*216 + kt)*512 + g] = (p==0 ? bw[o][i] : cw[p-1][o][i]*ssp[o])
// o = nt*128+row, i = jj*32+kc*8, kt = p*24+jj.
// ---------------------------------------------------------------------------
__global__ __launch_bounds__(256) void pack_b_t(
    const float* __restrict__ bw, const float* __restrict__ ssp,
    const float* __restrict__ cw, short8* __restrict__ Bt)
{
  __shared__ float ws[32][129];

  const int bid = blockIdx.x;          // nt*216 + kt
  const int nt = bid / KT_TILES;
  const int kt = bid % KT_TILES;
  const int p = kt / PJ, jj = kt % PJ;
  const int i0 = jj * 32;
  const int tid = threadIdx.x;

  const float* srcbase = (p == 0) ? bw : cw + (size_t)(p - 1) * OUT_D * IN_D;
  {
    const int c = tid & 7, r0 = tid >> 3;
    #pragma unroll
    for (int q = 0; q < 4; ++q) {
      int r = q * 32 + r0;
      f32x4 v = *(const f32x4*)(srcbase + (size_t)(nt * 128 + r) * IN_D + i0 + c * 4);
      #pragma unroll
      for (int e = 0; e < 4; ++e) ws[c * 4 + e][r] = v[e];
    }
  }
  __syncthreads();

  short8* dst = Bt + ((size_t)nt * KT_TILES + kt) * GRANA;
  #pragma unroll
  for (int c2 = 0; c2 < 2; ++c2) {
    int g = c2 * 256 + tid, row = g & 127, kc = g >> 7;
    float fac = (p == 0) ? 1.f : ssp[nt * 128 + row];
    short8 s;
    #pragma unroll
    for (int e = 0; e < 8; ++e)
      s[e] = (short)f2bf(ws[kc * 8 + e][row] * fac);
    dst[g] = s;
  }
}

// ---------------------------------------------------------------------------
// skan_gemm: identical to round-7 measured config (178us, MfmaUtil 32%).
// 128x128 tile, BK=32, 4 waves, dbuf LDS (33 KB), global_load_lds width-16
// on fully-sequential addresses, bijective XCD swizzle.
// ---------------------------------------------------------------------------
__global__ __launch_bounds__(256, 4) void skan_gemm(
    const short8* __restrict__ At, const short8* __restrict__ Bt,
    const float* __restrict__ ssp, const float* __restrict__ cb,
    float* __restrict__ out)
{
  __shared__ short8 Asm[2][GRANA];
  __shared__ short8 Bsm[2][GRANA];
  __shared__ float bias_sm[BN];

  // bijective XCD swizzle (nwg=588 = 8*73+4)
  const int bid0 = blockIdx.x;
  const int xcd = bid0 & 7;
  const int idx = bid0 >> 3;
  const int wgid = (xcd < 4 ? xcd * 74 : 4 * 74 + (xcd - 4) * 73) + idx;
  const int tm = wgid / NT_TILES, tn = wgid % NT_TILES;
  const int m0 = tm * BM, n0 = tn * BN;

  const int tid = threadIdx.x;
  const int lane = tid & 63, wid = tid >> 6;
  const int wm = wid >> 1, wn = wid & 1;
  const int lrow = lane & 15, lkb = lane >> 4;

  if (tid < BN) {
    int o = n0 + tid;
    float s = 0.f;
    #pragma unroll
    for (int f = 0; f < NUM_F; ++f) s += cb[f * OUT_D + o];
    bias_sm[tid] = s * ssp[o];
  }

  const short8* Abase = At + (size_t)tm * KT_TILES * GRANA;
  const short8* Bbase = Bt + (size_t)tn * KT_TILES * GRANA;

  auto STAGE = [&](int buf, int t) {
    const short8* as = Abase + (size_t)t * GRANA;
    const short8* bs = Bbase + (size_t)t * GRANA;
    #pragma unroll
    for (int c = 0; c < 2; ++c) {
      __builtin_amdgcn_global_load_lds(
          (const __attribute__((address_space(1))) void*)(as + c * 256 + tid),
          (__attribute__((address_space(3))) void*)&Asm[buf][c * 256 + tid],
          16, 0, 0);
      __builtin_amdgcn_global_load_lds(
          (const __attribute__((address_space(1))) void*)(bs + c * 256 + tid),
          (__attribute__((address_space(3))) void*)&Bsm[buf][c * 256 + tid],
          16, 0, 0);
    }
  };

  f32x4 acc[4][4];
  #pragma unroll
  for (int i = 0; i < 4; ++i)
    #pragma unroll
    for (int j = 0; j < 4; ++j)
      acc[i][j] = (f32x4){0.f, 0.f, 0.f, 0.f};

  STAGE(0, 0);
  for (int t = 0; t < KT_TILES; ++t) {
    const int cur = t & 1;
    __syncthreads();                          // tile t landed; buf cur^1 free
    if (t + 1 < KT_TILES) STAGE(cur ^ 1, t + 1);
    short8 af[4], bfr[4];
    #pragma unroll
    for (int q = 0; q < 4; ++q) {
      int base = lkb * 128 + q * 16 + lrow;   // granule = kc*128 + row, kc=lkb
      af[q]  = Asm[cur][base + wm * 64];
      bfr[q] = Bsm[cur][base + wn * 64];
    }
    #pragma unroll
    for (int i = 0; i < 4; ++i)
      #pragma unroll
      for (int j = 0; j < 4; ++j)
        acc[i][j] = __builtin_amdgcn_mfma_f32_16x16x32_bf16(af[i], bfr[j], acc[i][j], 0, 0, 0);
  }

  // epilogue: C/D layout col=lane&15, row=(lane>>4)*4+reg  (verified round 1)
  #pragma unroll
  for (int i = 0; i < 4; ++i) {
    int row = m0 + wm * 64 + i * 16 + lkb * 4;
    #pragma unroll
    for (int j = 0; j < 4; ++j) {
      int col = n0 + wn * 64 + j * 16 + lrow;
      float bia = bias_sm[wn * 64 + j * 16 + lrow];
      float* op = out + (size_t)row * OUT_D + col;
      op[0 * OUT_D] = acc[i][j][0] + bia;
      op[1 * OUT_D] = acc[i][j][1] + bia;
      op[2 * OUT_D] = acc[i][j][2] + bia;
      op[3 * OUT_D] = acc[i][j][3] + bia;
    }
  }
}

extern "C" void kernel_launch(void* const* d_in, const int* in_sizes, int n_in,
                              void* d_out, int out_size, void* d_ws, size_t ws_size,
                              hipStream_t stream) {
  (void)in_sizes; (void)n_in; (void)out_size; (void)ws_size;
  const float* x    = (const float*)d_in[0];
  const float* bw   = (const float*)d_in[1];
  const float* grid = (const float*)d_in[2];
  const float* ssp  = (const float*)d_in[3];
  const float* coef = (const float*)d_in[4];
  const float* cw   = (const float*)d_in[5];
  const float* cb   = (const float*)d_in[6];
  float* out = (float*)d_out;

  const size_t A_bytes = (size_t)MT_TILES * KT_TILES * GRANA * 16;  // 173,408,256
  short8* Aw = (short8*)d_ws;
  short8* Bw = (short8*)((char*)d_ws + A_bytes);

  pack_a_t<<<MT_TILES * PJ, 256, 0, stream>>>(x, grid, coef, Aw);
  pack_b_t<<<NT_TILES * KT_TILES, 256, 0, stream>>>(bw, ssp, cw, Bw);
  skan_gemm<<<MT_TILES * NT_TILES, 256, 0, stream>>>(Aw, Bw, ssp, cb, out);
}